// Round 1
// baseline (41417.023 us; speedup 1.0000x reference)
//
#include <hip/hip_runtime.h>

// TrendGRU: B=32768, T=512, H=24.
// Per batch element: sequential GRU over T steps, then 24->2 FC.
// 1 thread == 1 batch element. W_hh/biases staged in LDS (wave-uniform
// broadcast reads). Block=64 so 512 blocks cover all 256 CUs (2 blocks/CU).

#define GRU_H 24
#define GRU_T 512
#define BDIM 64

__device__ __forceinline__ float fast_rcp(float x) {
    return __builtin_amdgcn_rcpf(x);
}
__device__ __forceinline__ float sigmoid_f(float x) {
    return fast_rcp(1.0f + __expf(-x));
}
__device__ __forceinline__ float tanh_f(float x) {
    // 1 - 2/(exp(2x)+1); exp overflow -> inf -> 1, exp underflow -> 0 -> -1. No NaN.
    return 1.0f - 2.0f * fast_rcp(__expf(2.0f * x) + 1.0f);
}

__global__ __launch_bounds__(BDIM) void trend_gru_kernel(
    const float* __restrict__ x,     // (B, T)
    const float* __restrict__ W_ih,  // (72,)
    const float* __restrict__ b_ih,  // (72,)
    const float* __restrict__ W_hh,  // (72, 24) row-major, rows r,z,n
    const float* __restrict__ b_hh,  // (72,)
    const float* __restrict__ fc_w,  // (2, 24)
    const float* __restrict__ fc_b,  // (2,)
    float* __restrict__ out,         // (B, 2)
    int B)
{
    __shared__ float sW[72 * GRU_H];  // W_hh rows (96 B each, 16B-aligned)
    __shared__ float sWih[72];
    __shared__ float sBrz[48];        // b_ih[g]+b_hh[g] for g in [0,48) (r,z gates)
    __shared__ float sBhn[GRU_H];     // b_hh[48+j]
    __shared__ float sBxn[GRU_H];     // b_ih[48+j]
    __shared__ float sFc[2 * GRU_H];
    __shared__ float sFcB[2];

    for (int i = threadIdx.x; i < 72 * GRU_H; i += BDIM) sW[i] = W_hh[i];
    for (int i = threadIdx.x; i < 72; i += BDIM) {
        sWih[i] = W_ih[i];
        if (i < 48) {
            sBrz[i] = b_ih[i] + b_hh[i];
        } else {
            sBhn[i - 48] = b_hh[i];
            sBxn[i - 48] = b_ih[i];
        }
    }
    if (threadIdx.x < 2 * GRU_H) sFc[threadIdx.x] = fc_w[threadIdx.x];
    if (threadIdx.x < 2) sFcB[threadIdx.x] = fc_b[threadIdx.x];
    __syncthreads();

    const int b = blockIdx.x * BDIM + threadIdx.x;
    const float* xb = x + (size_t)b * GRU_T;

    float h[GRU_H];
#pragma unroll
    for (int j = 0; j < GRU_H; ++j) h[j] = 0.0f;

#pragma unroll 1
    for (int t = 0; t < GRU_T; ++t) {
        const float xt = xb[t];
        float hnew[GRU_H];
#pragma unroll
        for (int j = 0; j < GRU_H; ++j) {
            float ar = fmaf(xt, sWih[j],      sBrz[j]);
            float az = fmaf(xt, sWih[24 + j], sBrz[24 + j]);
            float an = sBhn[j];
            const float4* Wr = (const float4*)&sW[(j)      * GRU_H];
            const float4* Wz = (const float4*)&sW[(j + 24) * GRU_H];
            const float4* Wn = (const float4*)&sW[(j + 48) * GRU_H];
#pragma unroll
            for (int c = 0; c < 6; ++c) {
                const float4 wr = Wr[c];
                const float4 wz = Wz[c];
                const float4 wn = Wn[c];
                const float h0 = h[4 * c + 0], h1 = h[4 * c + 1];
                const float h2 = h[4 * c + 2], h3 = h[4 * c + 3];
                ar = fmaf(wr.x, h0, ar); ar = fmaf(wr.y, h1, ar);
                ar = fmaf(wr.z, h2, ar); ar = fmaf(wr.w, h3, ar);
                az = fmaf(wz.x, h0, az); az = fmaf(wz.y, h1, az);
                az = fmaf(wz.z, h2, az); az = fmaf(wz.w, h3, az);
                an = fmaf(wn.x, h0, an); an = fmaf(wn.y, h1, an);
                an = fmaf(wn.z, h2, an); an = fmaf(wn.w, h3, an);
            }
            const float r = sigmoid_f(ar);
            const float z = sigmoid_f(az);
            const float npre = fmaf(r, an, fmaf(xt, sWih[48 + j], sBxn[j]));
            const float n = tanh_f(npre);
            hnew[j] = fmaf(z, h[j] - n, n);   // (1-z)*n + z*h
        }
#pragma unroll
        for (int j = 0; j < GRU_H; ++j) h[j] = hnew[j];
    }

    float o0 = sFcB[0];
    float o1 = sFcB[1];
#pragma unroll
    for (int j = 0; j < GRU_H; ++j) {
        o0 = fmaf(h[j], sFc[j],          o0);
        o1 = fmaf(h[j], sFc[GRU_H + j],  o1);
    }
    out[(size_t)b * 2 + 0] = o0;
    out[(size_t)b * 2 + 1] = o1;
}

extern "C" void kernel_launch(void* const* d_in, const int* in_sizes, int n_in,
                              void* d_out, int out_size, void* d_ws, size_t ws_size,
                              hipStream_t stream) {
    const float* x    = (const float*)d_in[0];
    const float* W_ih = (const float*)d_in[1];
    const float* b_ih = (const float*)d_in[2];
    const float* W_hh = (const float*)d_in[3];
    const float* b_hh = (const float*)d_in[4];
    const float* fc_w = (const float*)d_in[5];
    const float* fc_b = (const float*)d_in[6];
    float* out = (float*)d_out;

    const int B = in_sizes[0] / GRU_T;  // 32768
    const int grid = B / BDIM;          // 512 blocks
    trend_gru_kernel<<<grid, BDIM, 0, stream>>>(x, W_ih, b_ih, W_hh, b_hh,
                                                fc_w, fc_b, out, B);
}

// Round 2
// 5303.762 us; speedup vs baseline: 7.8090x; 7.8090x over previous
//
#include <hip/hip_runtime.h>

// TrendGRU: B=32768, T=512, H=24.  1 thread == 1 batch element.
// R2: fix R1's hoist-then-spill catastrophe (compiler hoisted the LDS weight
// matrix into registers, spilled ~5.6KB/thread to scratch -> 48GB HBM reads).
// asm memory clobber at top of the t-loop forces per-iteration LDS reloads
// (wave-uniform ds_read_b128 broadcasts, conflict-free) and keeps live set
// ~100 VGPRs. Weights packed as 28-float rows: [W_hh(24) | w_ih | bias | 0 0]
// dotted with hx = [h(24) | xt | 1 | 0 | 0].

#define GRU_H 24
#define GRU_T 512
#define BDIM 64
#define RS 28   // padded row stride (7 float4)

__device__ __forceinline__ float fast_rcp(float x) {
    return __builtin_amdgcn_rcpf(x);
}
__device__ __forceinline__ float sigmoid_f(float x) {
    return fast_rcp(1.0f + __expf(-x));
}
__device__ __forceinline__ float tanh_f(float x) {
    // 1 - 2/(exp(2x)+1); exp overflow -> inf -> 1, underflow -> 0 -> -1. No NaN.
    return 1.0f - 2.0f * fast_rcp(__expf(2.0f * x) + 1.0f);
}

__global__ __launch_bounds__(BDIM) void trend_gru_kernel(
    const float* __restrict__ x,     // (B, T)
    const float* __restrict__ W_ih,  // (72,)
    const float* __restrict__ b_ih,  // (72,)
    const float* __restrict__ W_hh,  // (72, 24) rows r,z,n
    const float* __restrict__ b_hh,  // (72,)
    const float* __restrict__ fc_w,  // (2, 24)
    const float* __restrict__ fc_b,  // (2,)
    float* __restrict__ out,         // (B, 2)
    int B)
{
    // Row g: cols 0..23 = W_hh[g][:]; col 24 = w_ih[g] (r,z rows) / 0 (n rows);
    // col 25 = b_ih[g]+b_hh[g] (r,z rows) / b_hh[g] (n rows); cols 26,27 = 0.
    __shared__ float sRow[72 * RS];
    __shared__ float sXn[48];        // [0..23]=W_ih[48+j], [24..47]=b_ih[48+j]
    __shared__ float sFc[2 * GRU_H];
    __shared__ float sFcB[2];

    for (int i = threadIdx.x; i < 72 * RS; i += BDIM) {
        const int g = i / RS, c = i % RS;
        float v = 0.0f;
        if (c < 24)       v = W_hh[g * 24 + c];
        else if (c == 24) v = (g < 48) ? W_ih[g] : 0.0f;
        else if (c == 25) v = (g < 48) ? (b_ih[g] + b_hh[g]) : b_hh[g];
        sRow[i] = v;
    }
    if (threadIdx.x < 24) {
        sXn[threadIdx.x]      = W_ih[48 + threadIdx.x];
        sXn[24 + threadIdx.x] = b_ih[48 + threadIdx.x];
    }
    if (threadIdx.x < 2 * GRU_H) sFc[threadIdx.x] = fc_w[threadIdx.x];
    if (threadIdx.x < 2) sFcB[threadIdx.x] = fc_b[threadIdx.x];
    __syncthreads();

    const int b = blockIdx.x * BDIM + threadIdx.x;
    const float* xb = x + (size_t)b * GRU_T;

    float hx[RS];
#pragma unroll
    for (int i = 0; i < RS; ++i) hx[i] = 0.0f;
    hx[25] = 1.0f;   // bias lane

#pragma unroll 1
    for (int t = 0; t < GRU_T; ++t) {
        // Full memory clobber: LDS may have changed -> compiler must re-read
        // sRow/sXn THIS iteration. Prevents the hoist-then-spill from R1.
        asm volatile("" ::: "memory");

        const float xt = xb[t];
        hx[24] = xt;

        // n-gate input part: xnb[j] = xt * w_ih_n[j] + b_ih_n[j]
        float xnb[GRU_H];
        {
            const float4* w4 = (const float4*)&sXn[0];
            const float4* b4 = (const float4*)&sXn[24];
#pragma unroll
            for (int c = 0; c < 6; ++c) {
                const float4 w = w4[c];
                const float4 bb = b4[c];
                xnb[4 * c + 0] = fmaf(xt, w.x, bb.x);
                xnb[4 * c + 1] = fmaf(xt, w.y, bb.y);
                xnb[4 * c + 2] = fmaf(xt, w.z, bb.z);
                xnb[4 * c + 3] = fmaf(xt, w.w, bb.w);
            }
        }

        float hnew[GRU_H];
#pragma unroll
        for (int j = 0; j < GRU_H; ++j) {
            const float4* Rr = (const float4*)&sRow[(j)      * RS];
            const float4* Rz = (const float4*)&sRow[(24 + j) * RS];
            const float4* Rn = (const float4*)&sRow[(48 + j) * RS];
            float ar = 0.0f, az = 0.0f, an = 0.0f;
#pragma unroll
            for (int c = 0; c < 7; ++c) {
                const float4 wr = Rr[c];
                const float4 wz = Rz[c];
                const float4 wn = Rn[c];
                const float h0 = hx[4 * c + 0], h1 = hx[4 * c + 1];
                const float h2 = hx[4 * c + 2], h3 = hx[4 * c + 3];
                ar = fmaf(wr.x, h0, ar); ar = fmaf(wr.y, h1, ar);
                ar = fmaf(wr.z, h2, ar); ar = fmaf(wr.w, h3, ar);
                az = fmaf(wz.x, h0, az); az = fmaf(wz.y, h1, az);
                az = fmaf(wz.z, h2, az); az = fmaf(wz.w, h3, az);
                an = fmaf(wn.x, h0, an); an = fmaf(wn.y, h1, an);
                an = fmaf(wn.z, h2, an); an = fmaf(wn.w, h3, an);
            }
            const float r = sigmoid_f(ar);
            const float z = sigmoid_f(az);
            const float n = tanh_f(fmaf(r, an, xnb[j]));
            hnew[j] = fmaf(z, hx[j] - n, n);   // (1-z)*n + z*h
        }
#pragma unroll
        for (int j = 0; j < GRU_H; ++j) hx[j] = hnew[j];
    }

    float o0 = sFcB[0];
    float o1 = sFcB[1];
#pragma unroll
    for (int j = 0; j < GRU_H; ++j) {
        o0 = fmaf(hx[j], sFc[j],         o0);
        o1 = fmaf(hx[j], sFc[GRU_H + j], o1);
    }
    out[(size_t)b * 2 + 0] = o0;
    out[(size_t)b * 2 + 1] = o1;
}

extern "C" void kernel_launch(void* const* d_in, const int* in_sizes, int n_in,
                              void* d_out, int out_size, void* d_ws, size_t ws_size,
                              hipStream_t stream) {
    const float* x    = (const float*)d_in[0];
    const float* W_ih = (const float*)d_in[1];
    const float* b_ih = (const float*)d_in[2];
    const float* W_hh = (const float*)d_in[3];
    const float* b_hh = (const float*)d_in[4];
    const float* fc_w = (const float*)d_in[5];
    const float* fc_b = (const float*)d_in[6];
    float* out = (float*)d_out;

    const int B = in_sizes[0] / GRU_T;  // 32768
    const int grid = B / BDIM;          // 512 blocks -> 2 waves/CU
    trend_gru_kernel<<<grid, BDIM, 0, stream>>>(x, W_ih, b_ih, W_hh, b_hh,
                                                fc_w, fc_b, out, B);
}

// Round 3
// 659.865 us; speedup vs baseline: 62.7659x; 8.0376x over previous
//
#include <hip/hip_runtime.h>

// TrendGRU R3: per-wave MFMA GEMM formulation.
// B=32768 elems, T=512, H=24. Wave = 16 elements (M=16). Weights live in
// MFMA B-fragments (registers, shared across the wave) -- no per-thread
// weight reloads (R2's 137 GB LDS-traffic floor is eliminated).
// Precision: 3-term bf16 split packed into K: Whi*hh + Whi*hl + Wlo*hh
// (+ split x/bias), fp32 MFMA accumulation => ~fp32 end-to-end.
// K-stream per element m (bf16 slots, row stride 72 shorts = 144 B):
//   [0..23]=hh, [24..47]=hl, [48]=x_hi, [49]=x_lo, [50]=x_hi, [51]=1, [52]=1,
//   [53..71]=0/pad.  3 chained K=32 MFMA steps; step2 reuses step0's A frag.
// N-tiles (16 cols): 0,1=r; 2,3=z; 4,5=n_h; 6,7=n_x (n_x: step1 only).
// exp2 scaling folded into weights: r,z scaled by log2(e); n_h,n_x by 2*log2(e).
// No __syncthreads anywhere: LDS staging is wave-private, same-wave DS ops
// are ordered.

#define GRU_T 512
#define GRU_H 24

typedef __attribute__((ext_vector_type(8))) short bf16x8;
typedef __attribute__((ext_vector_type(4))) float f32x4;

__device__ __forceinline__ float bf16hi_f(float v) {
    unsigned u = __float_as_uint(v);
    u = (u + 0x7FFFu + ((u >> 16) & 1u)) & 0xFFFF0000u;
    return __uint_as_float(u);
}
__device__ __forceinline__ unsigned short bf16_rne(float v) {
    unsigned u = __float_as_uint(v);
    return (unsigned short)((u + 0x7FFFu + ((u >> 16) & 1u)) >> 16);
}
__device__ __forceinline__ f32x4 mfma16(bf16x8 a, bf16x8 b, f32x4 c) {
    return __builtin_amdgcn_mfma_f32_16x16x32_bf16(a, b, c, 0, 0, 0);
}
// a is pre-scaled by log2(e):  sigmoid(a/log2e) = 1/(1+2^-a)
__device__ __forceinline__ float sigf(float a) {
    return __builtin_amdgcn_rcpf(1.0f + __builtin_amdgcn_exp2f(-a));
}
// v is pre-scaled by 2*log2(e): tanh(v/(2 log2e)) = 1 - 2/(2^v + 1)
__device__ __forceinline__ float tnhf(float v) {
    return fmaf(-2.0f, __builtin_amdgcn_rcpf(1.0f + __builtin_amdgcn_exp2f(v)), 1.0f);
}

__global__ __launch_bounds__(256, 2) void trend_gru_mfma(
    const float* __restrict__ x,     // (B, T)
    const float* __restrict__ W_ih,  // (72,)
    const float* __restrict__ b_ih,  // (72,)
    const float* __restrict__ W_hh,  // (72, 24)
    const float* __restrict__ b_hh,  // (72,)
    const float* __restrict__ fc_w,  // (2, 24)
    const float* __restrict__ fc_b,  // (2,)
    float* __restrict__ out)         // (B, 2)
{
    const int lane = threadIdx.x & 63;
    const int wv   = threadIdx.x >> 6;
    const int n    = lane & 15;   // MFMA col (output row within tile) / A row m
    const int quad = lane >> 4;

    __shared__ __align__(16) short S_all[4][16 * 72];
    short* S = &S_all[wv][0];
    const int elem0 = blockIdx.x * 64 + wv * 16;

    const float L2E = 1.4426950408889634f;

    // ---- build B fragments (once; registers thereafter) ----
    // B lane layout (dual of verified A layout): col n = lane&15, k = quad*8+j.
    bf16x8 B[3][6];   // [K-step][tile 0..5: r0,r1,z0,z1,nh0,nh1]
    bf16x8 Bx[2];     // n_x tiles, K-step 1 only
#pragma unroll
    for (int s = 0; s < 3; ++s) {
#pragma unroll
        for (int tl = 0; tl < 6; ++tl) {
            const int g = tl >> 1;                    // 0=r,1=z,2=n_h
            const int jout = (tl & 1) * 16 + n;
            const bool valid = jout < GRU_H;
            const float sc = (g == 2) ? 2.0f * L2E : L2E;
            const int R = (g < 2) ? g * GRU_H + jout : 48 + jout;
            bf16x8 f;
#pragma unroll
            for (int j = 0; j < 8; ++j) {
                const int k = s * 32 + quad * 8 + j;
                float val = 0.0f;
                if (valid) {
                    if (k < 48) {
                        const int c = (k < 24) ? k : k - 24;
                        val = bf16hi_f(sc * W_hh[R * 24 + c]);
                    } else if (k < 53) {
                        const float wx = (g < 2) ? sc * W_ih[R] : 0.0f;
                        const float bb = sc * ((g < 2) ? (b_ih[R] + b_hh[R]) : b_hh[R]);
                        if (k == 48 || k == 49)      val = bf16hi_f(wx);
                        else if (k == 50)            val = wx - bf16hi_f(wx);
                        else if (k == 51)            val = bf16hi_f(bb);
                        else                         val = bb - bf16hi_f(bb);
                    } else if (k >= 64 && k < 88) {
                        const float w = sc * W_hh[R * 24 + (k - 64)];
                        val = w - bf16hi_f(w);       // Wlo, pairs with hh
                    }
                }
                f[j] = (short)bf16_rne(val);
            }
            B[s][tl] = f;
        }
    }
#pragma unroll
    for (int tl = 0; tl < 2; ++tl) {
        const int jout = tl * 16 + n;
        const bool valid = jout < GRU_H;
        const float sc = 2.0f * L2E;
        bf16x8 f;
#pragma unroll
        for (int j = 0; j < 8; ++j) {
            const int k = 32 + quad * 8 + j;   // step-1 k range
            float val = 0.0f;
            if (valid && k >= 48 && k < 53) {
                const float wx = sc * W_ih[48 + jout];
                const float bb = sc * b_ih[48 + jout];
                if (k == 48 || k == 49) val = bf16hi_f(wx);
                else if (k == 50)       val = wx - bf16hi_f(wx);
                else if (k == 51)       val = bf16hi_f(bb);
                else                    val = bb - bf16hi_f(bb);
            }
            f[j] = (short)bf16_rne(val);
        }
        Bx[tl] = f;
    }

    // ---- init S rows: h=0, constant 1.0 slots (51,52), zero pads ----
    if (lane < 16) {
        short* row = S + lane * 72;
        const int4 z4i = {0, 0, 0, 0};
        *(int4*)(row + 0)  = z4i;                  // hh 0..7
        *(int4*)(row + 8)  = z4i;                  // hh 8..15
        *(int4*)(row + 16) = z4i;                  // hh 16..23
        *(int4*)(row + 24) = z4i;                  // hl 0..7
        *(int4*)(row + 32) = z4i;                  // hl 8..15
        *(int4*)(row + 40) = z4i;                  // hl 16..23
        int4 c4; c4.x = 0; c4.y = 0x3F800000; c4.z = 0x00003F80; c4.w = 0;
        *(int4*)(row + 48) = c4;                   // slots 48..55: x slots + 1.0,1.0
        *(int4*)(row + 56) = z4i;
        *(int4*)(row + 64) = z4i;
    }

    // ---- per-lane FC weights ----
    const float fw00 = fc_w[n];
    const float fw01 = (n < 8) ? fc_w[16 + n] : 0.0f;
    const float fw10 = fc_w[24 + n];
    const float fw11 = (n < 8) ? fc_w[40 + n] : 0.0f;
    const float fcb0 = fc_b[0], fcb1 = fc_b[1];

    const float* xp = x + (size_t)(elem0 + n) * GRU_T;  // used by lanes<16 (quad==0, n=lane)
    float xv = (lane < 16) ? xp[0] : 0.0f;

    float h0[4] = {0.f, 0.f, 0.f, 0.f};   // lane's h for col j=n,    m=quad*4+r
    float h1[4] = {0.f, 0.f, 0.f, 0.f};   // lane's h for col j=16+n (n<8)

#pragma unroll 1
    for (int t = 0; t < GRU_T; ++t) {
        // stage x_t (lanes 0..15 own row m=lane)
        if (lane < 16) {
            const float xh = bf16hi_f(xv);
            const unsigned xhi = bf16_rne(xh);
            const unsigned xlo = bf16_rne(xv - xh);
            *(unsigned*)(S + lane * 72 + 48) = xhi | (xlo << 16);  // slots 48,49
            S[lane * 72 + 50] = (short)xhi;                        // slot 50
        }
        const float xnext = (lane < 16) ? xp[(t + 1 < GRU_T) ? t + 1 : t] : 0.0f;

        // A fragments: row m = n, k = quad*8+j
        const short* Sr = S + n * 72;
        const bf16x8 A0 = *(const bf16x8*)(Sr + quad * 8);        // slots 0..31
        const bf16x8 A1 = *(const bf16x8*)(Sr + 32 + quad * 8);   // slots 32..63

        const f32x4 z4 = {0.f, 0.f, 0.f, 0.f};
        f32x4 aR0 = mfma16(A0, B[0][0], z4); aR0 = mfma16(A1, B[1][0], aR0); aR0 = mfma16(A0, B[2][0], aR0);
        f32x4 aR1 = mfma16(A0, B[0][1], z4); aR1 = mfma16(A1, B[1][1], aR1); aR1 = mfma16(A0, B[2][1], aR1);
        f32x4 aZ0 = mfma16(A0, B[0][2], z4); aZ0 = mfma16(A1, B[1][2], aZ0); aZ0 = mfma16(A0, B[2][2], aZ0);
        f32x4 aZ1 = mfma16(A0, B[0][3], z4); aZ1 = mfma16(A1, B[1][3], aZ1); aZ1 = mfma16(A0, B[2][3], aZ1);
        f32x4 aN0 = mfma16(A0, B[0][4], z4); aN0 = mfma16(A1, B[1][4], aN0); aN0 = mfma16(A0, B[2][4], aN0);
        f32x4 aN1 = mfma16(A0, B[0][5], z4); aN1 = mfma16(A1, B[1][5], aN1); aN1 = mfma16(A0, B[2][5], aN1);
        const f32x4 aX0 = mfma16(A1, Bx[0], z4);
        const f32x4 aX1 = mfma16(A1, Bx[1], z4);

        // epilogue: gates + h update + bf16 split writeback (C-layout -> A rows)
#pragma unroll
        for (int r = 0; r < 4; ++r) {
            const int row = quad * 4 + r;
            {
                const float rr = sigf(aR0[r]);
                const float zz = sigf(aZ0[r]);
                const float nn = tnhf(fmaf(rr, aN0[r], aX0[r]));
                const float hn = fmaf(zz, h0[r] - nn, nn);
                h0[r] = hn;
                const float hh = bf16hi_f(hn);
                S[row * 72 + n]      = (short)bf16_rne(hh);
                S[row * 72 + 24 + n] = (short)bf16_rne(hn - hh);
            }
            if (n < 8) {
                const float rr = sigf(aR1[r]);
                const float zz = sigf(aZ1[r]);
                const float nn = tnhf(fmaf(rr, aN1[r], aX1[r]));
                const float hn = fmaf(zz, h1[r] - nn, nn);
                h1[r] = hn;
                const float hh = bf16hi_f(hn);
                S[row * 72 + 16 + n] = (short)bf16_rne(hh);
                S[row * 72 + 40 + n] = (short)bf16_rne(hn - hh);
            }
        }
        xv = xnext;
    }

    // ---- FC head: reduce over j (16 lanes of the quad hold cols) ----
#pragma unroll
    for (int r = 0; r < 4; ++r) {
        float p0 = h0[r] * fw00 + ((n < 8) ? h1[r] * fw01 : 0.0f);
        float p1 = h0[r] * fw10 + ((n < 8) ? h1[r] * fw11 : 0.0f);
#pragma unroll
        for (int m = 1; m < 16; m <<= 1) {
            p0 += __shfl_xor(p0, m, 16);
            p1 += __shfl_xor(p1, m, 16);
        }
        if (n == 0) {
            const int e = elem0 + quad * 4 + r;
            float2 o; o.x = p0 + fcb0; o.y = p1 + fcb1;
            *(float2*)(out + (size_t)e * 2) = o;
        }
    }
}

extern "C" void kernel_launch(void* const* d_in, const int* in_sizes, int n_in,
                              void* d_out, int out_size, void* d_ws, size_t ws_size,
                              hipStream_t stream) {
    const float* x    = (const float*)d_in[0];
    const float* W_ih = (const float*)d_in[1];
    const float* b_ih = (const float*)d_in[2];
    const float* W_hh = (const float*)d_in[3];
    const float* b_hh = (const float*)d_in[4];
    const float* fc_w = (const float*)d_in[5];
    const float* fc_b = (const float*)d_in[6];
    float* out = (float*)d_out;

    const int B = in_sizes[0] / GRU_T;      // 32768
    const int grid = B / 64;                // 512 blocks x 256 threads (4 waves)
    trend_gru_mfma<<<grid, 256, 0, stream>>>(x, W_ih, b_ih, W_hh, b_hh,
                                             fc_w, fc_b, out);
}

// Round 4
// 547.684 us; speedup vs baseline: 75.6222x; 1.2048x over previous
//
#include <hip/hip_runtime.h>

// TrendGRU R4: MFMA formulation with the precision split moved from h
// (per-step VALU cost) to W (one-time, baked into B-fragments).
// K=32 layout per element row: [0..23]=h(bf16 RNE) | 24=x_hi | 25=x_lo |
// 26=x_hi | 27=1.0 | 28=1.0 | 29..31=0.
// B-frags carry Whi (+x/bias hi&lo terms) and Wlo (h columns only):
//   gate = Whi*h + Wlo*h + Wih_hi*x_hi + Wih_hi*x_lo + Wih_lo*x_hi + b_hi + b_lo
// 14 MFMAs/wave/t (6 tiles x 2-chain + 2 n_x singles), 1 ds_read_b128 A-frag,
// h writeback = 1 RNE + 1 ds_write_b16 per gate-triple slot.
// exp2 scaling folded into weights: r,z by log2(e); n by 2*log2(e).
// Wave-private LDS, no __syncthreads. h kept fp32 in registers for the
// z*(h-n) path; only the matmul input is bf16-quantized.

#define GRU_T 512
#define RS 40   // LDS row stride in shorts (80 B, 16B-aligned, bank-balanced)

typedef __attribute__((ext_vector_type(8))) short bf16x8;
typedef __attribute__((ext_vector_type(4))) float f32x4;

__device__ __forceinline__ float bf16hi_f(float v) {   // RNE-to-bf16, as float
    unsigned u = __float_as_uint(v);
    u = (u + 0x7FFFu + ((u >> 16) & 1u)) & 0xFFFF0000u;
    return __uint_as_float(u);
}
__device__ __forceinline__ unsigned bf16_rne(float v) {
    unsigned u = __float_as_uint(v);
    return (u + 0x7FFFu + ((u >> 16) & 1u)) >> 16;
}
__device__ __forceinline__ f32x4 mfma16(bf16x8 a, bf16x8 b, f32x4 c) {
    return __builtin_amdgcn_mfma_f32_16x16x32_bf16(a, b, c, 0, 0, 0);
}
// a pre-scaled by log2(e):  sigmoid(a/log2e) = 1/(1+2^-a)
__device__ __forceinline__ float sigf(float a) {
    return __builtin_amdgcn_rcpf(1.0f + __builtin_amdgcn_exp2f(-a));
}
// v pre-scaled by 2*log2(e): tanh(v/(2 log2e)) = 1 - 2/(2^v + 1)
__device__ __forceinline__ float tnhf(float v) {
    return fmaf(-2.0f, __builtin_amdgcn_rcpf(1.0f + __builtin_amdgcn_exp2f(v)), 1.0f);
}

__global__ __launch_bounds__(256, 2) void trend_gru_mfma(
    const float* __restrict__ x,     // (B, T)
    const float* __restrict__ W_ih,  // (72,)
    const float* __restrict__ b_ih,  // (72,)
    const float* __restrict__ W_hh,  // (72, 24)
    const float* __restrict__ b_hh,  // (72,)
    const float* __restrict__ fc_w,  // (2, 24)
    const float* __restrict__ fc_b,  // (2,)
    float* __restrict__ out)         // (B, 2)
{
    const int lane = threadIdx.x & 63;
    const int wv   = threadIdx.x >> 6;
    const int n    = lane & 15;   // B col (output unit) / A row (element)
    const int quad = lane >> 4;

    __shared__ __align__(16) unsigned short S_all[4][16 * RS];
    unsigned short* S16 = &S_all[wv][0];
    const int elem0 = blockIdx.x * 64 + wv * 16;

    const float L2E = 1.4426950408889634f;

    // ---- build B fragments once (registers; wave-shared via MFMA) ----
    // B lane layout (verified in R3): col = lane&15, k = quad*8 + j.
    bf16x8 Bh[6], Bl[6], Bx[2];
#pragma unroll
    for (int tl = 0; tl < 6; ++tl) {
        const int g = tl >> 1;                  // 0=r, 1=z, 2=n_h
        const int jout = (tl & 1) * 16 + n;
        const bool valid = jout < 24;
        const float sc = (g == 2) ? 2.0f * L2E : L2E;
        const int R = (g < 2) ? g * 24 + jout : 48 + jout;
        const int Rc = valid ? R : 0;
        const float wx = (g < 2 && valid) ? sc * W_ih[Rc] : 0.0f;
        const float bb = valid ? sc * ((g < 2) ? (b_ih[Rc] + b_hh[Rc]) : b_hh[Rc]) : 0.0f;
        const float wxh = bf16hi_f(wx), bbh = bf16hi_f(bb);
        bf16x8 fh, fl;
#pragma unroll
        for (int j = 0; j < 8; ++j) {
            const int k = quad * 8 + j;
            float vh = 0.0f, vl = 0.0f;
            if (valid && k < 24) {
                const float w  = sc * W_hh[Rc * 24 + k];
                const float wh = bf16hi_f(w);
                vh = wh; vl = w - wh;
            } else if (valid) {
                if (k == 24 || k == 25) vh = wxh;          // Wih_hi * (x_hi, x_lo)
                else if (k == 26)       vh = wx - wxh;     // Wih_lo * x_hi
                else if (k == 27)       vh = bbh;          // b_hi * 1
                else if (k == 28)       vh = bb - bbh;     // b_lo * 1
            }
            fh[j] = (short)bf16_rne(vh);
            fl[j] = (short)bf16_rne(vl);
        }
        Bh[tl] = fh; Bl[tl] = fl;
    }
#pragma unroll
    for (int tl = 0; tl < 2; ++tl) {            // n_x tiles
        const int jout = tl * 16 + n;
        const bool valid = jout < 24;
        const int R = 48 + (valid ? jout : 0);
        const float sc = 2.0f * L2E;
        const float wx = valid ? sc * W_ih[R] : 0.0f;
        const float bb = valid ? sc * b_ih[R] : 0.0f;
        const float wxh = bf16hi_f(wx), bbh = bf16hi_f(bb);
        bf16x8 f;
#pragma unroll
        for (int j = 0; j < 8; ++j) {
            const int k = quad * 8 + j;
            float v = 0.0f;
            if (k == 24 || k == 25) v = wxh;
            else if (k == 26)       v = wx - wxh;
            else if (k == 27)       v = bbh;
            else if (k == 28)       v = bb - bbh;
            f[j] = (short)bf16_rne(v);
        }
        Bx[tl] = f;
    }

    // ---- init S rows: h=0, x slots 0, slots 27/28 = 1.0 bf16 ----
    if (lane < 16) {
        unsigned short* row = S16 + lane * RS;
        const int4 z4i = {0, 0, 0, 0};
        *(int4*)(row)      = z4i;               // h 0..7
        *(int4*)(row + 8)  = z4i;               // h 8..15
        *(int4*)(row + 16) = z4i;               // h 16..23
        int4 c4;
        c4.x = 0;                               // slots 24,25 (x, staged per t)
        c4.y = 0x3F800000;                      // slot 26 (staged), slot 27 = 1.0
        c4.z = 0x00003F80;                      // slot 28 = 1.0, slot 29 = 0
        c4.w = 0;                               // slots 30,31
        *(int4*)(row + 24) = c4;
    }

    // ---- per-lane FC weights ----
    const float fw00 = fc_w[n];
    const float fw01 = (n < 8) ? fc_w[16 + n] : 0.0f;
    const float fw10 = fc_w[24 + n];
    const float fw11 = (n < 8) ? fc_w[40 + n] : 0.0f;
    const float fcb0 = fc_b[0], fcb1 = fc_b[1];

    const float* xp = x + (size_t)(elem0 + n) * GRU_T;   // lanes<16 use it
    float xv = (lane < 16) ? xp[0] : 0.0f;

    float h0[4] = {0.f, 0.f, 0.f, 0.f};   // col j=n,    row m=quad*4+r
    float h1[4] = {0.f, 0.f, 0.f, 0.f};   // col j=16+n (valid n<8)

#pragma unroll 1
    for (int t = 0; t < GRU_T; ++t) {
        // stage x_t (lanes 0..15 own element row m=lane)
        if (lane < 16) {
            const float xh = bf16hi_f(xv);
            const unsigned xhi = __float_as_uint(xh) >> 16;
            const unsigned xlo = bf16_rne(xv - xh);
            *(unsigned*)(S16 + lane * RS + 24) = xhi | (xlo << 16);  // slots 24,25
            S16[lane * RS + 26] = (unsigned short)xhi;               // slot 26
        }
        const float xnext = (lane < 16) ? xp[(t + 1 < GRU_T) ? t + 1 : t] : 0.0f;

        // A fragment: row m = n, k = quad*8+j  (one b128)
        const bf16x8 A0 = *(const bf16x8*)(S16 + n * RS + quad * 8);

        const f32x4 z4 = {0.f, 0.f, 0.f, 0.f};
        f32x4 aR0 = mfma16(A0, Bh[0], z4); aR0 = mfma16(A0, Bl[0], aR0);
        f32x4 aR1 = mfma16(A0, Bh[1], z4); aR1 = mfma16(A0, Bl[1], aR1);
        f32x4 aZ0 = mfma16(A0, Bh[2], z4); aZ0 = mfma16(A0, Bl[2], aZ0);
        f32x4 aZ1 = mfma16(A0, Bh[3], z4); aZ1 = mfma16(A0, Bl[3], aZ1);
        f32x4 aN0 = mfma16(A0, Bh[4], z4); aN0 = mfma16(A0, Bl[4], aN0);
        f32x4 aN1 = mfma16(A0, Bh[5], z4); aN1 = mfma16(A0, Bl[5], aN1);
        const f32x4 aX0 = mfma16(A0, Bx[0], z4);
        const f32x4 aX1 = mfma16(A0, Bx[1], z4);

        // epilogue: gates + h update + single-bf16 writeback
#pragma unroll
        for (int r = 0; r < 4; ++r) {
            unsigned short* wrow = S16 + (quad * 4 + r) * RS;
            {
                const float rr = sigf(aR0[r]);
                const float zz = sigf(aZ0[r]);
                const float nn = tnhf(fmaf(rr, aN0[r], aX0[r]));
                const float hn = fmaf(zz, h0[r] - nn, nn);
                h0[r] = hn;
                wrow[n] = (unsigned short)bf16_rne(hn);
            }
            {
                // unpredicated compute (cols >=24 have all-zero B -> benign)
                const float rr = sigf(aR1[r]);
                const float zz = sigf(aZ1[r]);
                const float nn = tnhf(fmaf(rr, aN1[r], aX1[r]));
                const float hn = fmaf(zz, h1[r] - nn, nn);
                h1[r] = hn;
                if (n < 8) wrow[16 + n] = (unsigned short)bf16_rne(hn);
            }
        }
        xv = xnext;
    }

    // ---- FC head: reduce over the 16 lanes of each quad ----
#pragma unroll
    for (int r = 0; r < 4; ++r) {
        float p0 = h0[r] * fw00 + ((n < 8) ? h1[r] * fw01 : 0.0f);
        float p1 = h0[r] * fw10 + ((n < 8) ? h1[r] * fw11 : 0.0f);
#pragma unroll
        for (int m = 1; m < 16; m <<= 1) {
            p0 += __shfl_xor(p0, m, 16);
            p1 += __shfl_xor(p1, m, 16);
        }
        if (n == 0) {
            const int e = elem0 + quad * 4 + r;
            float2 o; o.x = p0 + fcb0; o.y = p1 + fcb1;
            *(float2*)(out + (size_t)e * 2) = o;
        }
    }
}

extern "C" void kernel_launch(void* const* d_in, const int* in_sizes, int n_in,
                              void* d_out, int out_size, void* d_ws, size_t ws_size,
                              hipStream_t stream) {
    const float* x    = (const float*)d_in[0];
    const float* W_ih = (const float*)d_in[1];
    const float* b_ih = (const float*)d_in[2];
    const float* W_hh = (const float*)d_in[3];
    const float* b_hh = (const float*)d_in[4];
    const float* fc_w = (const float*)d_in[5];
    const float* fc_b = (const float*)d_in[6];
    float* out = (float*)d_out;

    const int B = in_sizes[0] / GRU_T;      // 32768
    const int grid = B / 64;                // 512 blocks x 256 threads (4 waves)
    trend_gru_mfma<<<grid, 256, 0, stream>>>(x, W_ih, b_ih, W_hh, b_hh,
                                             fc_w, fc_b, out);
}